// Round 10
// baseline (153.852 us; speedup 1.0000x reference)
//
#include <hip/hip_runtime.h>

// Problem constants (reference: B=8, T=2048, C=1024, H=64)
#define B_ 8
#define T_ 2048
#define C_ 1024
#define H_ 64

typedef __bf16 bf16x8 __attribute__((ext_vector_type(8)));
typedef float  f32x4  __attribute__((ext_vector_type(4)));
typedef unsigned short u16x8 __attribute__((ext_vector_type(8)));
typedef float  f32x4v __attribute__((ext_vector_type(4)));   // native vec for nt-loads

// round-half-up f32 -> bf16 bits
__device__ __forceinline__ unsigned short f2bf(float f) {
    unsigned u = __builtin_bit_cast(unsigned, f);
    u += 0x8000u;
    return (unsigned short)(u >> 16);
}

__device__ __forceinline__ float bf2f(unsigned short v) {
    unsigned u = ((unsigned)v) << 16;
    return __builtin_bit_cast(float, u);
}

__device__ __forceinline__ unsigned pack2(float lo, float hi) {
    unsigned a = __builtin_bit_cast(unsigned, lo) + 0x8000u;
    unsigned b = __builtin_bit_cast(unsigned, hi) + 0x8000u;
    return (a >> 16) | (b & 0xffff0000u);
}

union U8 { unsigned u32[4]; u16x8 v; };

__device__ __forceinline__ u16x8 cvt8v(f32x4v f0, f32x4v f1) {
    U8 r;
    r.u32[0] = pack2(f0.x, f0.y);
    r.u32[1] = pack2(f0.z, f0.w);
    r.u32[2] = pack2(f1.x, f1.y);
    r.u32[3] = pack2(f1.z, f1.w);
    return r.v;
}

__device__ __forceinline__ bf16x8 load8_bf(const unsigned short* p) {
    return __builtin_bit_cast(bf16x8, *(const u16x8*)p);
}

// Fragment-major layouts (contiguous 1KB-per-wave loads):
//   Qf/Kf[b][t16][part][l16*32 + quad*8 + j]   (t16 = seq/16, part = h/32)
//   Vf[b][s32][ht][l16*32 + quad*8 + j]        (s32 = seq/32, ht = h/16)
//   Wtf[nt][kk][l16*32 + quad*8 + j]           (nt = ncol/16 of 192, kk = c/32)

// ---------------------------------------------------------------------------
// Kernel 0: pack Wq,Wk,Wv (fp32 [C][H]) straight into fragment-major Wtf.
// ---------------------------------------------------------------------------
__global__ void cast_weights(const float* __restrict__ Wq,
                             const float* __restrict__ Wk,
                             const float* __restrict__ Wv,
                             unsigned short* __restrict__ Wtf) {
    int idx = blockIdx.x * blockDim.x + threadIdx.x;   // 0 .. 192*1024-1
    int n   = idx % 192;        // global out col
    int c   = idx / 192;        // k index
    int w   = n >> 6;
    int h   = n & 63;
    const float* W = (w == 0) ? Wq : (w == 1) ? Wk : Wv;
    int nt = n >> 4, l16 = n & 15;
    int kk = c >> 5, quad = (c >> 3) & 3, j = c & 7;
    Wtf[(size_t)(nt * 32 + kk) * 512 + l16 * 32 + quad * 8 + j] =
        f2bf(W[(size_t)c * H_ + h]);
}

// ---------------------------------------------------------------------------
// Kernel 1: fused QKV projection, v9 = v8 + NON-TEMPORAL x loads/output
// stores.  Theory: v8's 196 MB of Wtf re-reads (512 blocks x 384 KB) were
// served from LLC at streaming rate because the 67 MB x stream evicted Wtf
// from per-XCD L2.  nt-loads for x keep it out of L2 -> Wtf stays
// L2-resident -> its re-reads run at L2 BW.  Output stores also nt (consumed
// next kernel; no reuse here).
// ---------------------------------------------------------------------------
__global__ __launch_bounds__(256) void qkv_proj(
        const float* __restrict__ x,
        const unsigned short* __restrict__ Wtf,
        unsigned short* __restrict__ Qf,
        unsigned short* __restrict__ Kf,
        unsigned short* __restrict__ Vf) {
    __shared__ __attribute__((aligned(16))) unsigned short As_[32 * 512]; // 32 KB

    const int tid  = threadIdx.x;
    const int ns   = tid >> 6;           // wave = n-quarter (3 n-tiles)
    const int lane = tid & 63;
    const int l16  = lane & 15;
    const int quad = lane >> 4;
    const size_t r0 = (size_t)blockIdx.x * 32;
    const int bb    = (int)(r0 >> 11);
    const int tloc0 = (int)(r0 & (T_ - 1));
    const int t16_0 = tloc0 >> 4;
    const int s32   = tloc0 >> 5;

    f32x4 acc[6];   // [ms*3 + i]
#pragma unroll
    for (int i = 0; i < 6; i++) acc[i] = (f32x4){0.f, 0.f, 0.f, 0.f};

    const int sw   = l16 & 7;
    const int loff = l16 * 32 + quad * 8;

    for (int p = 0; p < 2; p++) {
        if (p) __syncthreads();          // phase-0 reads done before overwrite
        // ---- stage x[r0..r0+32)[p*512..+512) -> As_ (bf16, XOR-swizzled)
        //      NON-TEMPORAL: do not allocate x in L2 (protect Wtf residency)
#pragma unroll
        for (int i = 0; i < 8; i++) {
            int c   = i * 256 + tid;     // granule 0..2047
            int row = c >> 6;            // 0..31
            int g   = c & 63;            // 16B group within 512-k row
            const float* sp = x + (r0 + row) * C_ + p * 512 + g * 8;
            f32x4v f0 = __builtin_nontemporal_load((const f32x4v*)sp);
            f32x4v f1 = __builtin_nontemporal_load((const f32x4v*)(sp + 4));
            int off = row * 512 + ((g & ~7) + ((g & 7) ^ (row & 7))) * 8;
            *(u16x8*)(&As_[off]) = cvt8v(f0, f1);
        }
        __syncthreads();

#pragma unroll 4
        for (int kc = 0; kc < 16; kc++) {
            int g  = kc * 4 + quad;
            int gs = ((g & ~7) + ((g & 7) ^ sw)) * 8;
            bf16x8 a0 = load8_bf(&As_[l16 * 512 + gs]);
            bf16x8 a1 = load8_bf(&As_[(16 + l16) * 512 + gs]);
            int kk = p * 16 + kc;
#pragma unroll
            for (int i = 0; i < 3; i++) {
                bf16x8 b = load8_bf(Wtf + (size_t)((ns * 3 + i) * 32 + kk) * 512 + loff);
                acc[i]     = __builtin_amdgcn_mfma_f32_16x16x32_bf16(a0, b, acc[i],     0, 0, 0);
                acc[3 + i] = __builtin_amdgcn_mfma_f32_16x16x32_bf16(a1, b, acc[3 + i], 0, 0, 0);
            }
        }
    }

    // ---- epilogue: assemble fragment-major chunks in LDS, then coalesced copy
    __syncthreads();                     // all ds_reads done; reuse As_ as E
    unsigned short* E = As_;             // 12 chunks x 512 u16 = 12 KB
#pragma unroll
    for (int i = 0; i < 3; i++) {
        int nt = ns * 3 + i;
#pragma unroll
        for (int msI = 0; msI < 2; msI++) {
#pragma unroll
            for (int r = 0; r < 4; r++) {
                unsigned short bv = f2bf(acc[msI * 3 + i][r]);
                int off;
                int ch;
                if (nt < 4) {            // Q
                    ch  = msI * 2 + (nt >> 1);
                    off = (quad * 4 + r) * 32 + ((nt & 1) * 2 + (l16 >> 3)) * 8 + (l16 & 7);
                } else if (nt < 8) {     // K
                    int nk = nt - 4;
                    ch  = 4 + msI * 2 + (nk >> 1);
                    off = (quad * 4 + r) * 32 + ((nk & 1) * 2 + (l16 >> 3)) * 8 + (l16 & 7);
                } else {                 // V
                    int w32 = msI * 16 + quad * 4 + r;
                    ch  = 8 + (nt - 8);
                    off = l16 * 32 + (w32 >> 3) * 8 + (w32 & 7);
                }
                E[ch * 512 + off] = bv;
            }
        }
    }
    __syncthreads();

#pragma unroll
    for (int i = 0; i < 3; i++) {
        int gi = i * 256 + tid;          // 0..767
        int ch = gi >> 6;
        int g  = gi & 63;
        unsigned short* dst;
        if (ch < 4) {
            dst = Qf + ((size_t)(bb * 128 + t16_0 + (ch >> 1)) * 2 + (ch & 1)) * 512;
        } else if (ch < 8) {
            int c2 = ch - 4;
            dst = Kf + ((size_t)(bb * 128 + t16_0 + (c2 >> 1)) * 2 + (c2 & 1)) * 512;
        } else {
            dst = Vf + ((size_t)(bb * 64 + s32) * 4 + (ch - 8)) * 512;
        }
        __builtin_nontemporal_store(*(const u16x8*)(&E[ch * 512 + g * 8]),
                                    (u16x8*)(dst + g * 8));
    }
}

// ---------------------------------------------------------------------------
// Kernel 2: flash attention, v8 (32 q-rows/block, 4-way KV split) — unchanged.
// ---------------------------------------------------------------------------
#define PROW 33   // u32 per P^T row
#define OMS2 66   // u16 per O-merge row

__global__ __launch_bounds__(256) void attn(
        const unsigned short* __restrict__ Qf,
        const unsigned short* __restrict__ Kf,
        const unsigned short* __restrict__ Vf,
        float* __restrict__ out) {
    __shared__ unsigned int ps_[4 * 32 * PROW];     // 16.9 KB
    __shared__ unsigned short Om_[4 * 32 * OMS2];   // 16.9 KB
    __shared__ float mred_[4][32];
    __shared__ float lred_[4][32];

    const int tid  = threadIdx.x;
    const int wave = tid >> 6;            // KV-split index 0..3
    const int lane = tid & 63;
    const int l16  = lane & 15;
    const int quad = lane >> 4;
    const int b    = blockIdx.x & 7;      // XCD-affinity: batch = XCD
    const int qt32 = blockIdx.x >> 3;     // 0..63
    const int q0   = qt32 * 32;
    const int tdiag = qt32 >> 1;          // diagonal 64-key tile index

    const int loff = l16 * 32 + quad * 8;

    // Q as B-operand, two q-groups
    bf16x8 qf[2][2];
#pragma unroll
    for (int qg = 0; qg < 2; qg++) {
        const unsigned short* Qfb = Qf + (size_t)((b * 128 + qt32 * 2 + qg) * 2) * 512;
        qf[qg][0] = load8_bf(Qfb + loff);
        qf[qg][1] = load8_bf(Qfb + 512 + loff);
    }

    f32x4 o[8];   // [qg*4 + ht]
#pragma unroll
    for (int i = 0; i < 8; i++) o[i] = (f32x4){0.f, 0.f, 0.f, 0.f};
    float m_run[2] = {-1e30f, -1e30f}, l_run[2] = {0.f, 0.f};

    const float scale = 0.125f;  // 1/sqrt(H)
    const unsigned short* Kfb = Kf + (size_t)b * 128 * 1024;
    const unsigned short* Vfb = Vf + (size_t)b * 64 * 2048;
    unsigned int* Pw = &ps_[wave * 32 * PROW];

    for (int t = wave; t <= tdiag; t += 4) {
        // V^T A-frags: contiguous 1KB loads, issued EARLY (softmax-independent)
        bf16x8 vf[8];
#pragma unroll
        for (int ks = 0; ks < 2; ks++)
#pragma unroll
            for (int ht = 0; ht < 4; ht++)
                vf[ht * 2 + ks] = load8_bf(
                    Vfb + ((size_t)(t * 2 + ks) * 4 + ht) * 512 + loff);

        // S^T = K * Q^T for both q-groups (K frags shared)
        f32x4 s[2][4];
#pragma unroll
        for (int nt = 0; nt < 4; nt++) {
            const unsigned short* kp = Kfb + (size_t)(t * 4 + nt) * 1024;
            bf16x8 kf0 = load8_bf(kp + loff);
            bf16x8 kf1 = load8_bf(kp + 512 + loff);
#pragma unroll
            for (int qg = 0; qg < 2; qg++) {
                f32x4 z = (f32x4){0.f, 0.f, 0.f, 0.f};
                z = __builtin_amdgcn_mfma_f32_16x16x32_bf16(kf0, qf[qg][0], z, 0, 0, 0);
                z = __builtin_amdgcn_mfma_f32_16x16x32_bf16(kf1, qf[qg][1], z, 0, 0, 0);
                s[qg][nt] = z;   // S^T[s = t*64+nt*16+quad*4+r][q = q0+qg*16+l16]
            }
        }

#pragma unroll
        for (int qg = 0; qg < 2; qg++)
#pragma unroll
            for (int nt = 0; nt < 4; nt++)
#pragma unroll
                for (int r = 0; r < 4; r++) s[qg][nt][r] *= scale;

        if (t == tdiag) {   // causal: mask s > q
#pragma unroll
            for (int qg = 0; qg < 2; qg++) {
                int q = q0 + qg * 16 + l16;
#pragma unroll
                for (int nt = 0; nt < 4; nt++)
#pragma unroll
                    for (int r = 0; r < 4; r++) {
                        int key = t * 64 + nt * 16 + quad * 4 + r;
                        if (key > q) s[qg][nt][r] = -1e30f;
                    }
            }
        }

        // per-lane softmax per q-group: in-lane tree + 2 cross-quad shuffles
#pragma unroll
        for (int qg = 0; qg < 2; qg++) {
            float m0 = fmaxf(fmaxf(s[qg][0][0], s[qg][0][1]), fmaxf(s[qg][0][2], s[qg][0][3]));
            float m1 = fmaxf(fmaxf(s[qg][1][0], s[qg][1][1]), fmaxf(s[qg][1][2], s[qg][1][3]));
            float m2 = fmaxf(fmaxf(s[qg][2][0], s[qg][2][1]), fmaxf(s[qg][2][2], s[qg][2][3]));
            float m3 = fmaxf(fmaxf(s[qg][3][0], s[qg][3][1]), fmaxf(s[qg][3][2], s[qg][3][3]));
            float mx = fmaxf(fmaxf(m0, m1), fmaxf(m2, m3));
            mx = fmaxf(mx, __shfl_xor(mx, 16));
            mx = fmaxf(mx, __shfl_xor(mx, 32));
            const float m_new = fmaxf(m_run[qg], mx);
            const float alpha = __expf(m_run[qg] - m_new);
            m_run[qg] = m_new;

            float rs = 0.f;
#pragma unroll
            for (int nt = 0; nt < 4; nt++) {
#pragma unroll
                for (int i = 0; i < 2; i++) {
                    float p0 = __expf(s[qg][nt][2 * i]     - m_new);
                    float p1 = __expf(s[qg][nt][2 * i + 1] - m_new);
                    rs += p0 + p1;
                    Pw[(qg * 16 + l16) * PROW + nt * 8 + quad * 2 + i] = pack2(p0, p1);
                }
            }
            rs += __shfl_xor(rs, 16);
            rs += __shfl_xor(rs, 32);
            l_run[qg] = l_run[qg] * alpha + rs;

#pragma unroll
            for (int ht = 0; ht < 4; ht++)
#pragma unroll
                for (int r = 0; r < 4; r++) o[qg * 4 + ht][r] *= alpha;
        }

        // O^T += V^T * P^T (V frags shared across q-groups)
#pragma unroll
        for (int ks = 0; ks < 2; ks++) {
#pragma unroll
            for (int qg = 0; qg < 2; qg++) {
                bf16x8 pB = __builtin_bit_cast(bf16x8,
                    *(const u16x8*)(&Pw[(qg * 16 + l16) * PROW + ks * 16 + quad * 4]));
#pragma unroll
                for (int ht = 0; ht < 4; ht++)
                    o[qg * 4 + ht] = __builtin_amdgcn_mfma_f32_16x16x32_bf16(
                        vf[ht * 2 + ks], pB, o[qg * 4 + ht], 0, 0, 0);
            }
        }
    }

    // ---- 4-way LSE merge (O partials bf16) ----
#pragma unroll
    for (int qg = 0; qg < 2; qg++) {
#pragma unroll
        for (int ht = 0; ht < 4; ht++)
#pragma unroll
            for (int r = 0; r < 4; r++)
                Om_[(wave * 32 + qg * 16 + l16) * OMS2 + ht * 16 + quad * 4 + r] =
                    f2bf(o[qg * 4 + ht][r]);
        if (quad == 0) {
            mred_[wave][qg * 16 + l16] = m_run[qg];
            lred_[wave][qg * 16 + l16] = l_run[qg];
        }
    }
    __syncthreads();

    // finalize: thread -> (q, h); coalesced out write
    const int hcol = tid & 63;
    const int qr0  = tid >> 6;   // 0..3
#pragma unroll
    for (int qq = 0; qq < 8; qq++) {
        const int q = qr0 + qq * 4;
        float M = -1e30f;
#pragma unroll
        for (int w = 0; w < 4; w++) M = fmaxf(M, mred_[w][q]);
        float lt = 0.f, ov = 0.f;
#pragma unroll
        for (int w = 0; w < 4; w++) {
            float e = __expf(mred_[w][q] - M);
            lt += e * lred_[w][q];
            ov += e * bf2f(Om_[(w * 32 + q) * OMS2 + hcol]);
        }
        out[((size_t)b * T_ + q0 + q) * H_ + hcol] = ov / lt;
    }
}

// ---------------------------------------------------------------------------
extern "C" void kernel_launch(void* const* d_in, const int* in_sizes, int n_in,
                              void* d_out, int out_size, void* d_ws, size_t ws_size,
                              hipStream_t stream) {
    const float* x  = (const float*)d_in[0];
    const float* Wq = (const float*)d_in[1];
    const float* Wk = (const float*)d_in[2];
    const float* Wv = (const float*)d_in[3];
    float* out = (float*)d_out;

    unsigned short* Qf  = (unsigned short*)d_ws;
    unsigned short* Kf  = Qf + (size_t)B_ * T_ * H_;
    unsigned short* Vf  = Kf + (size_t)B_ * T_ * H_;
    unsigned short* Wtf = Vf + (size_t)B_ * T_ * H_;

    cast_weights<<<(192 * C_) / 256, 256, 0, stream>>>(Wq, Wk, Wv, Wtf);
    qkv_proj<<<B_ * T_ / 32, 256, 0, stream>>>(x, Wtf, Qf, Kf, Vf);
    attn<<<B_ * (T_ / 32), 256, 0, stream>>>(Qf, Kf, Vf, out);
}